// Round 7
// baseline (477.952 us; speedup 1.0000x reference)
//
#include <hip/hip_runtime.h>

#define N_NODES 100000
#define N_EDGES 800000
#define DIM 64
#define BN_EPS 1e-5f

// ===========================================================================
// CSR build: count in-degrees, exclusive scan, scatter edges grouped by dst.
// Edge payload packed as int2 {src, bits(w)}.
// ===========================================================================

__global__ __launch_bounds__(256) void k_zero_deg(int* __restrict__ deg) {
    int i = blockIdx.x * blockDim.x + threadIdx.x;
    if (i < N_NODES) deg[i] = 0;
}

__global__ __launch_bounds__(256) void k_count(const int* __restrict__ dst,
                                               int* __restrict__ deg) {
    int e = blockIdx.x * blockDim.x + threadIdx.x;
    if (e < N_EDGES) atomicAdd(&deg[dst[e]], 1);
}

// 98 blocks x 256 threads x 4 elems = 100352 >= N. Per-block exclusive scan.
__global__ __launch_bounds__(256) void k_scan1(const int* __restrict__ deg,
                                               int* __restrict__ row_off,
                                               int* __restrict__ block_sums) {
    __shared__ int sdata[256];
    int tid = threadIdx.x;
    int base = blockIdx.x * 1024 + tid * 4;
    int4 v = make_int4(0, 0, 0, 0);
    if (base < N_NODES) v = *(const int4*)(deg + base);   // N % 4 == 0
    int tsum = v.x + v.y + v.z + v.w;
    sdata[tid] = tsum;
    __syncthreads();
    for (int off = 1; off < 256; off <<= 1) {
        int t = (tid >= off) ? sdata[tid - off] : 0;
        __syncthreads();
        sdata[tid] += t;
        __syncthreads();
    }
    int excl = sdata[tid] - tsum;
    if (base < N_NODES) {
        int4 o;
        o.x = excl;
        o.y = o.x + v.x;
        o.z = o.y + v.y;
        o.w = o.z + v.z;
        *(int4*)(row_off + base) = o;
    }
    if (tid == 255) block_sums[blockIdx.x] = sdata[255];
}

__global__ __launch_bounds__(128) void k_scan2(int* __restrict__ block_sums) {
    __shared__ int sdata[128];
    int tid = threadIdx.x;
    int v = (tid < 98) ? block_sums[tid] : 0;
    sdata[tid] = v;
    __syncthreads();
    for (int off = 1; off < 128; off <<= 1) {
        int t = (tid >= off) ? sdata[tid - off] : 0;
        __syncthreads();
        sdata[tid] += t;
        __syncthreads();
    }
    if (tid < 98) block_sums[tid] = sdata[tid] - v;
}

__global__ __launch_bounds__(256) void k_scan3(const int* __restrict__ deg,
                                               int* __restrict__ row_off,
                                               int* __restrict__ cursor,
                                               float* __restrict__ dinv,
                                               const int* __restrict__ block_sums) {
    int tid = threadIdx.x;
    int base = blockIdx.x * 1024 + tid * 4;
    if (base >= N_NODES) return;
    int p = block_sums[blockIdx.x];
    int4 r = *(const int4*)(row_off + base);
    r.x += p; r.y += p; r.z += p; r.w += p;
    *(int4*)(row_off + base) = r;
    *(int4*)(cursor + base) = r;
    int4 d = *(const int4*)(deg + base);
    float4 di;
    di.x = rsqrtf((float)(d.x + 1));
    di.y = rsqrtf((float)(d.y + 1));
    di.z = rsqrtf((float)(d.z + 1));
    di.w = rsqrtf((float)(d.w + 1));
    *(float4*)(dinv + base) = di;
}

__global__ __launch_bounds__(256) void k_build(const int* __restrict__ ei,
                                               const float* __restrict__ dinv,
                                               int* __restrict__ cursor,
                                               int2* __restrict__ edges) {
    int e = blockIdx.x * blockDim.x + threadIdx.x;
    if (e >= N_EDGES) return;
    int s = ei[e];
    int d = ei[N_EDGES + e];
    int pos = atomicAdd(&cursor[d], 1);
    edges[pos] = make_int2(s, __float_as_int(dinv[s] * dinv[d]));
}

// ===========================================================================
// Tail algebra: W3p = W3 @ pW1, b3p = b3 @ pW1 + pb1  (one block)
// ===========================================================================
__global__ __launch_bounds__(256) void k_fuse_w3(const float* __restrict__ W3,
                                                 const float* __restrict__ b3,
                                                 const float* __restrict__ pW1,
                                                 const float* __restrict__ pb1,
                                                 float* __restrict__ W3p,
                                                 float* __restrict__ b3p) {
    int tid = threadIdx.x;
    int c = tid & 63;
    int kbase = (tid >> 6) * 16;
    for (int k = kbase; k < kbase + 16; ++k) {
        float acc = 0.f;
#pragma unroll 8
        for (int j = 0; j < 64; ++j)
            acc = fmaf(W3[k * 64 + j], pW1[j * 64 + c], acc);
        W3p[k * 64 + c] = acc;
    }
    if (tid < 64) {
        float acc = pb1[c];
#pragma unroll 8
        for (int j = 0; j < 64; ++j)
            acc = fmaf(b3[j], pW1[j * 64 + c], acc);
        b3p[c] = acc;
    }
}

// ===========================================================================
// Gather helper: one wave accumulates one node's aggregated row (lane = col).
// ===========================================================================
__device__ __forceinline__ float gather_node(const float* __restrict__ xin,
                                             const int* __restrict__ row_off,
                                             const int* __restrict__ deg,
                                             const int2* __restrict__ edges,
                                             const float* __restrict__ dinv,
                                             int node, int lane) {
    float di = dinv[node];
    float acc = xin[(size_t)node * DIM + lane] * (di * di);
    int beg = __builtin_amdgcn_readfirstlane(row_off[node]);
    int len = __builtin_amdgcn_readfirstlane(deg[node]);
    int end = beg + len;
    int k = beg;
    for (; k + 8 <= end; k += 8) {
        int2 e0 = edges[k + 0];
        int2 e1 = edges[k + 1];
        int2 e2 = edges[k + 2];
        int2 e3 = edges[k + 3];
        int2 e4 = edges[k + 4];
        int2 e5 = edges[k + 5];
        int2 e6 = edges[k + 6];
        int2 e7 = edges[k + 7];
        float v0 = xin[(size_t)e0.x * DIM + lane];
        float v1 = xin[(size_t)e1.x * DIM + lane];
        float v2 = xin[(size_t)e2.x * DIM + lane];
        float v3 = xin[(size_t)e3.x * DIM + lane];
        float v4 = xin[(size_t)e4.x * DIM + lane];
        float v5 = xin[(size_t)e5.x * DIM + lane];
        float v6 = xin[(size_t)e6.x * DIM + lane];
        float v7 = xin[(size_t)e7.x * DIM + lane];
        acc = fmaf(__int_as_float(e0.y), v0, acc);
        acc = fmaf(__int_as_float(e1.y), v1, acc);
        acc = fmaf(__int_as_float(e2.y), v2, acc);
        acc = fmaf(__int_as_float(e3.y), v3, acc);
        acc = fmaf(__int_as_float(e4.y), v4, acc);
        acc = fmaf(__int_as_float(e5.y), v5, acc);
        acc = fmaf(__int_as_float(e6.y), v6, acc);
        acc = fmaf(__int_as_float(e7.y), v7, acc);
    }
    for (; k < end; ++k) {
        int2 e = edges[k];
        acc = fmaf(__int_as_float(e.y), xin[(size_t)e.x * DIM + lane], acc);
    }
    return acc;
}

// 64 FMAs of a 4-row x 4-col x 4-k outer-product step
#define GEMM_STEP(SX, SW)                                                      \
    {                                                                          \
        float4 a0 = *(const float4*)&SX[(r0 + 0) * 64 + k4 * 4];               \
        float4 a1 = *(const float4*)&SX[(r0 + 1) * 64 + k4 * 4];               \
        float4 a2 = *(const float4*)&SX[(r0 + 2) * 64 + k4 * 4];               \
        float4 a3 = *(const float4*)&SX[(r0 + 3) * 64 + k4 * 4];               \
        float4 b0 = *(const float4*)&SW[(k4 * 4 + 0) * 64 + c0];               \
        float4 b1 = *(const float4*)&SW[(k4 * 4 + 1) * 64 + c0];               \
        float4 b2 = *(const float4*)&SW[(k4 * 4 + 2) * 64 + c0];               \
        float4 b3 = *(const float4*)&SW[(k4 * 4 + 3) * 64 + c0];               \
        const float* ap[4] = {&a0.x, &a1.x, &a2.x, &a3.x};                     \
        _Pragma("unroll") for (int i = 0; i < 4; ++i) {                        \
            float x0 = ap[i][0], x1 = ap[i][1], x2 = ap[i][2], x3 = ap[i][3];  \
            acc[i][0] = fmaf(x0, b0.x, acc[i][0]);                             \
            acc[i][1] = fmaf(x0, b0.y, acc[i][1]);                             \
            acc[i][2] = fmaf(x0, b0.z, acc[i][2]);                             \
            acc[i][3] = fmaf(x0, b0.w, acc[i][3]);                             \
            acc[i][0] = fmaf(x1, b1.x, acc[i][0]);                             \
            acc[i][1] = fmaf(x1, b1.y, acc[i][1]);                             \
            acc[i][2] = fmaf(x1, b1.z, acc[i][2]);                             \
            acc[i][3] = fmaf(x1, b1.w, acc[i][3]);                             \
            acc[i][0] = fmaf(x2, b2.x, acc[i][0]);                             \
            acc[i][1] = fmaf(x2, b2.y, acc[i][1]);                             \
            acc[i][2] = fmaf(x2, b2.z, acc[i][2]);                             \
            acc[i][3] = fmaf(x2, b2.w, acc[i][3]);                             \
            acc[i][0] = fmaf(x3, b3.x, acc[i][0]);                             \
            acc[i][1] = fmaf(x3, b3.y, acc[i][1]);                             \
            acc[i][2] = fmaf(x3, b3.z, acc[i][2]);                             \
            acc[i][3] = fmaf(x3, b3.w, acc[i][3]);                             \
        }                                                                      \
    }

// ===========================================================================
// Fused GCN layer: block = 64 nodes. 4 waves gather 16 nodes each into the
// sX LDS tile (registers only in flight), then register-tiled 64x64 GEMM
// with fused bias + BN + ReLU epilogue. mode: 0 = bias, 2 = bias+BN+ReLU
// ===========================================================================
__global__ __launch_bounds__(256) void k_layer(const float* __restrict__ xin,
                                               const int* __restrict__ row_off,
                                               const int* __restrict__ deg,
                                               const int2* __restrict__ edges,
                                               const float* __restrict__ dinv,
                                               const float* __restrict__ W,
                                               const float* __restrict__ bias,
                                               const float* __restrict__ bng,
                                               const float* __restrict__ bnb,
                                               const float* __restrict__ bnm,
                                               const float* __restrict__ bnv,
                                               float* __restrict__ out,
                                               int mode) {
    __shared__ float sW[4096];
    __shared__ float sX[4096];
    int tid = threadIdx.x;
    int base = blockIdx.x * 64;

    // stage W (no dependency on gather; barrier below covers both)
    for (int i = tid; i < 1024; i += 256)
        ((float4*)sW)[i] = ((const float4*)W)[i];

    int lane = tid & 63;
    int wv = tid >> 6;
    for (int i = 0; i < 16; ++i) {
        int node = base + wv * 16 + i;
        float acc = 0.f;
        if (node < N_NODES)
            acc = gather_node(xin, row_off, deg, edges, dinv, node, lane);
        sX[(wv * 16 + i) * 64 + lane] = acc;
    }
    __syncthreads();

    int cq = tid & 15, rq = tid >> 4;
    int c0 = cq * 4, r0 = rq * 4;
    float acc[4][4];
#pragma unroll
    for (int i = 0; i < 4; ++i)
#pragma unroll
        for (int j = 0; j < 4; ++j) acc[i][j] = 0.f;
#pragma unroll 4
    for (int k4 = 0; k4 < 16; ++k4) GEMM_STEP(sX, sW)

    float4 bv = *(const float4*)&bias[c0];
    if (mode == 2) {
        float4 g = *(const float4*)&bng[c0];
        float4 bb = *(const float4*)&bnb[c0];
        float4 m = *(const float4*)&bnm[c0];
        float4 vv = *(const float4*)&bnv[c0];
        float A0 = g.x * rsqrtf(vv.x + BN_EPS);
        float A1 = g.y * rsqrtf(vv.y + BN_EPS);
        float A2 = g.z * rsqrtf(vv.z + BN_EPS);
        float A3 = g.w * rsqrtf(vv.w + BN_EPS);
        float B0 = (bv.x - m.x) * A0 + bb.x;
        float B1 = (bv.y - m.y) * A1 + bb.y;
        float B2 = (bv.z - m.z) * A2 + bb.z;
        float B3 = (bv.w - m.w) * A3 + bb.w;
#pragma unroll
        for (int i = 0; i < 4; ++i) {
            int row = base + r0 + i;
            if (row >= N_NODES) break;
            float4 o;
            o.x = fmaxf(0.f, fmaf(acc[i][0], A0, B0));
            o.y = fmaxf(0.f, fmaf(acc[i][1], A1, B1));
            o.z = fmaxf(0.f, fmaf(acc[i][2], A2, B2));
            o.w = fmaxf(0.f, fmaf(acc[i][3], A3, B3));
            *(float4*)(out + (size_t)row * DIM + c0) = o;
        }
    } else {
#pragma unroll
        for (int i = 0; i < 4; ++i) {
            int row = base + r0 + i;
            if (row >= N_NODES) break;
            float4 o;
            o.x = acc[i][0] + bv.x;
            o.y = acc[i][1] + bv.y;
            o.z = acc[i][2] + bv.z;
            o.w = acc[i][3] + bv.w;
            *(float4*)(out + (size_t)row * DIM + c0) = o;
        }
    }
}

// ===========================================================================
// Layer 3 + predictor, fully fused:
// out = tanh( Agg(x) @ W3p + b3p ) @ pW2 + pb2
// Gather -> sX; GEMM(W3p); tanh back into sX; re-stage sW with pW2; GEMM.
// LDS stays 32 KB (5 blocks/CU).
// ===========================================================================
__global__ __launch_bounds__(256) void k_layer3_tail(const float* __restrict__ xin,
                                                     const int* __restrict__ row_off,
                                                     const int* __restrict__ deg,
                                                     const int2* __restrict__ edges,
                                                     const float* __restrict__ dinv,
                                                     const float* __restrict__ W3p,
                                                     const float* __restrict__ b3p,
                                                     const float* __restrict__ pW2,
                                                     const float* __restrict__ pb2,
                                                     float* __restrict__ out) {
    __shared__ float sW[4096];
    __shared__ float sX[4096];
    int tid = threadIdx.x;
    int base = blockIdx.x * 64;

    for (int i = tid; i < 1024; i += 256)
        ((float4*)sW)[i] = ((const float4*)W3p)[i];

    int lane = tid & 63;
    int wv = tid >> 6;
    for (int i = 0; i < 16; ++i) {
        int node = base + wv * 16 + i;
        float acc = 0.f;
        if (node < N_NODES)
            acc = gather_node(xin, row_off, deg, edges, dinv, node, lane);
        sX[(wv * 16 + i) * 64 + lane] = acc;
    }
    __syncthreads();

    int cq = tid & 15, rq = tid >> 4;
    int c0 = cq * 4, r0 = rq * 4;
    float acc[4][4];

    // ---- GEMM 1: sX @ W3p ----
#pragma unroll
    for (int i = 0; i < 4; ++i)
#pragma unroll
        for (int j = 0; j < 4; ++j) acc[i][j] = 0.f;
#pragma unroll 4
    for (int k4 = 0; k4 < 16; ++k4) GEMM_STEP(sX, sW)
    __syncthreads();   // all reads of sX and sW done

    // tanh + bias back into sX; re-stage sW with pW2
    {
        float4 bv = *(const float4*)&b3p[c0];
#pragma unroll
        for (int i = 0; i < 4; ++i) {
            float4 h;
            h.x = tanhf(acc[i][0] + bv.x);
            h.y = tanhf(acc[i][1] + bv.y);
            h.z = tanhf(acc[i][2] + bv.z);
            h.w = tanhf(acc[i][3] + bv.w);
            *(float4*)&sX[(r0 + i) * 64 + c0] = h;
        }
    }
    for (int i = tid; i < 1024; i += 256)
        ((float4*)sW)[i] = ((const float4*)pW2)[i];
    __syncthreads();

    // ---- GEMM 2: sX @ pW2 ----
#pragma unroll
    for (int i = 0; i < 4; ++i)
#pragma unroll
        for (int j = 0; j < 4; ++j) acc[i][j] = 0.f;
#pragma unroll 4
    for (int k4 = 0; k4 < 16; ++k4) GEMM_STEP(sX, sW)

    float4 bv = *(const float4*)&pb2[c0];
#pragma unroll
    for (int i = 0; i < 4; ++i) {
        int row = base + r0 + i;
        if (row >= N_NODES) break;
        float4 o;
        o.x = acc[i][0] + bv.x;
        o.y = acc[i][1] + bv.y;
        o.z = acc[i][2] + bv.z;
        o.w = acc[i][3] + bv.w;
        *(float4*)(out + (size_t)row * DIM + c0) = o;
    }
}

// ===========================================================================
extern "C" void kernel_launch(void* const* d_in, const int* in_sizes, int n_in,
                              void* d_out, int out_size, void* d_ws, size_t ws_size,
                              hipStream_t stream) {
    const float* x     = (const float*)d_in[0];
    const int*   ei    = (const int*)d_in[1];
    const float* W1    = (const float*)d_in[2];
    const float* b1    = (const float*)d_in[3];
    const float* W2    = (const float*)d_in[4];
    const float* b2    = (const float*)d_in[5];
    const float* W3    = (const float*)d_in[6];
    const float* b3    = (const float*)d_in[7];
    const float* bn1_g = (const float*)d_in[8];
    const float* bn1_b = (const float*)d_in[9];
    const float* bn1_m = (const float*)d_in[10];
    const float* bn1_v = (const float*)d_in[11];
    const float* bn2_g = (const float*)d_in[12];
    const float* bn2_b = (const float*)d_in[13];
    const float* bn2_m = (const float*)d_in[14];
    const float* bn2_v = (const float*)d_in[15];
    const float* pW1   = (const float*)d_in[16];
    const float* pb1   = (const float*)d_in[17];
    const float* pW2   = (const float*)d_in[18];
    const float* pb2   = (const float*)d_in[19];
    float* out = (float*)d_out;

    char* ws = (char*)d_ws;
    int*   deg      = (int*)ws;                      ws += 100352 * 4;
    int*   row_off  = (int*)ws;                      ws += 100352 * 4;
    int*   cursor   = (int*)ws;                      ws += 100352 * 4;
    int*   bsums    = (int*)ws;                      ws += 128 * 4;
    int2*  edges    = (int2*)ws;                     ws += (size_t)N_EDGES * 8;
    float* dinv     = (float*)ws;                    ws += 100352 * 4;
    float* W3p      = (float*)ws;                    ws += 4096 * 4;
    float* b3p      = (float*)ws;                    ws += 64 * 4;
    float* bufA     = (float*)ws;                    ws += (size_t)N_NODES * DIM * 4;
    float* bufB     = (float*)ws;

    const int blk = 256;
    int gN    = (N_NODES + blk - 1) / blk;       // 391
    int gE    = (N_EDGES + blk - 1) / blk;       // 3125
    int gScan = 98;
    int gTile = (N_NODES + 63) / 64;             // 1563

    // ---- CSR build (once, reused by all 3 layers) ----
    k_zero_deg<<<gN, blk, 0, stream>>>(deg);
    k_count<<<gE, blk, 0, stream>>>(ei + N_EDGES, deg);
    k_scan1<<<gScan, blk, 0, stream>>>(deg, row_off, bsums);
    k_scan2<<<1, 128, 0, stream>>>(bsums);
    k_scan3<<<gScan, blk, 0, stream>>>(deg, row_off, cursor, dinv, bsums);
    k_build<<<gE, blk, 0, stream>>>(ei, dinv, cursor, edges);
    k_fuse_w3<<<1, blk, 0, stream>>>(W3, b3, pW1, pb1, W3p, b3p);

    // ---- 3 fused layers (agg + GEMM [+ tail]) ----
    k_layer<<<gTile, blk, 0, stream>>>(x, row_off, deg, edges, dinv,
                                       W1, b1, bn1_g, bn1_b, bn1_m, bn1_v, bufA, 2);
    k_layer<<<gTile, blk, 0, stream>>>(bufA, row_off, deg, edges, dinv,
                                       W2, b2, bn2_g, bn2_b, bn2_m, bn2_v, bufB, 2);
    k_layer3_tail<<<gTile, blk, 0, stream>>>(bufB, row_off, deg, edges, dinv,
                                             W3p, b3p, pW2, pb2, out);
}

// Round 8
// 392.290 us; speedup vs baseline: 1.2184x; 1.2184x over previous
//
#include <hip/hip_runtime.h>

#define N_NODES 100000
#define N_EDGES 800000
#define DIM 64
#define BN_EPS 1e-5f
#define LDX 68   // sX row stride (floats): 16B-aligned, rows 0/4/8/12 -> 2-way banks (free)

// ===========================================================================
// CSR build: count in-degrees, exclusive scan over PADDED degrees (mult of 8),
// scatter edges grouped by dst, then fill pad slots with {self, w=0}.
// Edge payload packed as int2 {src, bits(w)}.
// ===========================================================================

__global__ __launch_bounds__(256) void k_zero_deg(int* __restrict__ deg) {
    int i = blockIdx.x * blockDim.x + threadIdx.x;
    if (i < N_NODES) deg[i] = 0;
}

__global__ __launch_bounds__(256) void k_count(const int* __restrict__ dst,
                                               int* __restrict__ deg) {
    int e = blockIdx.x * blockDim.x + threadIdx.x;
    if (e < N_EDGES) atomicAdd(&deg[dst[e]], 1);
}

// 98 blocks x 256 threads x 4 elems = 100352 >= N. Scan of padded degrees.
__global__ __launch_bounds__(256) void k_scan1(const int* __restrict__ deg,
                                               int* __restrict__ row_off,
                                               int* __restrict__ block_sums) {
    __shared__ int sdata[256];
    int tid = threadIdx.x;
    int base = blockIdx.x * 1024 + tid * 4;
    int4 v = make_int4(0, 0, 0, 0);
    if (base < N_NODES) {
        int4 d = *(const int4*)(deg + base);   // N % 4 == 0
        v.x = (d.x + 7) & ~7;
        v.y = (d.y + 7) & ~7;
        v.z = (d.z + 7) & ~7;
        v.w = (d.w + 7) & ~7;
    }
    int tsum = v.x + v.y + v.z + v.w;
    sdata[tid] = tsum;
    __syncthreads();
    for (int off = 1; off < 256; off <<= 1) {
        int t = (tid >= off) ? sdata[tid - off] : 0;
        __syncthreads();
        sdata[tid] += t;
        __syncthreads();
    }
    int excl = sdata[tid] - tsum;
    if (base < N_NODES) {
        int4 o;
        o.x = excl;
        o.y = o.x + v.x;
        o.z = o.y + v.y;
        o.w = o.z + v.z;
        *(int4*)(row_off + base) = o;
    }
    if (tid == 255) block_sums[blockIdx.x] = sdata[255];
}

__global__ __launch_bounds__(128) void k_scan2(int* __restrict__ block_sums) {
    __shared__ int sdata[128];
    int tid = threadIdx.x;
    int v = (tid < 98) ? block_sums[tid] : 0;
    sdata[tid] = v;
    __syncthreads();
    for (int off = 1; off < 128; off <<= 1) {
        int t = (tid >= off) ? sdata[tid - off] : 0;
        __syncthreads();
        sdata[tid] += t;
        __syncthreads();
    }
    if (tid < 98) block_sums[tid] = sdata[tid] - v;
}

__global__ __launch_bounds__(256) void k_scan3(const int* __restrict__ deg,
                                               int* __restrict__ row_off,
                                               int* __restrict__ cursor,
                                               float* __restrict__ dinv,
                                               const int* __restrict__ block_sums) {
    int tid = threadIdx.x;
    int base = blockIdx.x * 1024 + tid * 4;
    if (base >= N_NODES) return;
    int p = block_sums[blockIdx.x];
    int4 r = *(const int4*)(row_off + base);
    r.x += p; r.y += p; r.z += p; r.w += p;
    *(int4*)(row_off + base) = r;
    *(int4*)(cursor + base) = r;
    int4 d = *(const int4*)(deg + base);
    float4 di;
    di.x = rsqrtf((float)(d.x + 1));
    di.y = rsqrtf((float)(d.y + 1));
    di.z = rsqrtf((float)(d.z + 1));
    di.w = rsqrtf((float)(d.w + 1));
    *(float4*)(dinv + base) = di;
}

__global__ __launch_bounds__(256) void k_build(const int* __restrict__ ei,
                                               const float* __restrict__ dinv,
                                               int* __restrict__ cursor,
                                               int2* __restrict__ edges) {
    int e = blockIdx.x * blockDim.x + threadIdx.x;
    if (e >= N_EDGES) return;
    int s = ei[e];
    int d = ei[N_EDGES + e];
    int pos = atomicAdd(&cursor[d], 1);
    edges[pos] = make_int2(s, __float_as_int(dinv[s] * dinv[d]));
}

// fill pad slots [row_off+deg, row_off+pdeg) with {self, 0}
__global__ __launch_bounds__(256) void k_pad(const int* __restrict__ deg,
                                             const int* __restrict__ row_off,
                                             int2* __restrict__ edges) {
    int n = blockIdx.x * blockDim.x + threadIdx.x;
    if (n >= N_NODES) return;
    int d = deg[n];
    int start = row_off[n] + d;
    int end = row_off[n] + ((d + 7) & ~7);
    int2 dummy = make_int2(n, 0);
    for (int p = start; p < end; ++p) edges[p] = dummy;
}

// ===========================================================================
// Tail algebra: W3p = W3 @ pW1, b3p = b3 @ pW1 + pb1  (one block)
// ===========================================================================
__global__ __launch_bounds__(256) void k_fuse_w3(const float* __restrict__ W3,
                                                 const float* __restrict__ b3,
                                                 const float* __restrict__ pW1,
                                                 const float* __restrict__ pb1,
                                                 float* __restrict__ W3p,
                                                 float* __restrict__ b3p) {
    int tid = threadIdx.x;
    int c = tid & 63;
    int kbase = (tid >> 6) * 16;
    for (int k = kbase; k < kbase + 16; ++k) {
        float acc = 0.f;
#pragma unroll 8
        for (int j = 0; j < 64; ++j)
            acc = fmaf(W3[k * 64 + j], pW1[j * 64 + c], acc);
        W3p[k * 64 + c] = acc;
    }
    if (tid < 64) {
        float acc = pb1[c];
#pragma unroll 8
        for (int j = 0; j < 64; ++j)
            acc = fmaf(b3[j], pW1[j * 64 + c], acc);
        b3p[c] = acc;
    }
}

// ===========================================================================
// Aggregation: one 64-lane wave per node, lane = feature column.
// CSR segments padded to x8 -> only the fully-pipelined 8-deep loop runs.
// Edge metadata via wave-uniform scalar loads (readfirstlane).
// out[n] = dinv[n]^2*x[n] + sum_e w_e*x[src_e]
// ===========================================================================
__global__ __launch_bounds__(256) void k_aggregate(const float* __restrict__ xin,
                                                   const int* __restrict__ row_off,
                                                   const int* __restrict__ deg,
                                                   const int2* __restrict__ edges,
                                                   const float* __restrict__ dinv,
                                                   float* __restrict__ out) {
    int lane = threadIdx.x & 63;
    int node = blockIdx.x * 4 + (threadIdx.x >> 6);   // grid = 25000 exact
    float di = dinv[node];
    float acc = xin[(size_t)node * DIM + lane] * (di * di);
    int beg = __builtin_amdgcn_readfirstlane(row_off[node]);
    int lenp = (__builtin_amdgcn_readfirstlane(deg[node]) + 7) & ~7;
    int end = beg + lenp;
    for (int k = beg; k < end; k += 8) {
        int2 e0 = edges[k + 0];
        int2 e1 = edges[k + 1];
        int2 e2 = edges[k + 2];
        int2 e3 = edges[k + 3];
        int2 e4 = edges[k + 4];
        int2 e5 = edges[k + 5];
        int2 e6 = edges[k + 6];
        int2 e7 = edges[k + 7];
        float v0 = xin[(size_t)e0.x * DIM + lane];
        float v1 = xin[(size_t)e1.x * DIM + lane];
        float v2 = xin[(size_t)e2.x * DIM + lane];
        float v3 = xin[(size_t)e3.x * DIM + lane];
        float v4 = xin[(size_t)e4.x * DIM + lane];
        float v5 = xin[(size_t)e5.x * DIM + lane];
        float v6 = xin[(size_t)e6.x * DIM + lane];
        float v7 = xin[(size_t)e7.x * DIM + lane];
        acc = fmaf(__int_as_float(e0.y), v0, acc);
        acc = fmaf(__int_as_float(e1.y), v1, acc);
        acc = fmaf(__int_as_float(e2.y), v2, acc);
        acc = fmaf(__int_as_float(e3.y), v3, acc);
        acc = fmaf(__int_as_float(e4.y), v4, acc);
        acc = fmaf(__int_as_float(e5.y), v5, acc);
        acc = fmaf(__int_as_float(e6.y), v6, acc);
        acc = fmaf(__int_as_float(e7.y), v7, acc);
    }
    out[(size_t)node * DIM + lane] = acc;
}

// 64 FMAs of a 4-row x 4-col x 4-k outer-product step (sX stride = LDX)
#define GEMM_STEP(SX, SW)                                                      \
    {                                                                          \
        float4 a0 = *(const float4*)&SX[(r0 + 0) * LDX + k4 * 4];              \
        float4 a1 = *(const float4*)&SX[(r0 + 1) * LDX + k4 * 4];              \
        float4 a2 = *(const float4*)&SX[(r0 + 2) * LDX + k4 * 4];              \
        float4 a3 = *(const float4*)&SX[(r0 + 3) * LDX + k4 * 4];              \
        float4 b0 = *(const float4*)&SW[(k4 * 4 + 0) * 64 + c0];               \
        float4 b1 = *(const float4*)&SW[(k4 * 4 + 1) * 64 + c0];               \
        float4 b2 = *(const float4*)&SW[(k4 * 4 + 2) * 64 + c0];               \
        float4 b3 = *(const float4*)&SW[(k4 * 4 + 3) * 64 + c0];               \
        const float* ap[4] = {&a0.x, &a1.x, &a2.x, &a3.x};                     \
        _Pragma("unroll") for (int i = 0; i < 4; ++i) {                        \
            float x0 = ap[i][0], x1 = ap[i][1], x2 = ap[i][2], x3 = ap[i][3];  \
            acc[i][0] = fmaf(x0, b0.x, acc[i][0]);                             \
            acc[i][1] = fmaf(x0, b0.y, acc[i][1]);                             \
            acc[i][2] = fmaf(x0, b0.z, acc[i][2]);                             \
            acc[i][3] = fmaf(x0, b0.w, acc[i][3]);                             \
            acc[i][0] = fmaf(x1, b1.x, acc[i][0]);                             \
            acc[i][1] = fmaf(x1, b1.y, acc[i][1]);                             \
            acc[i][2] = fmaf(x1, b1.z, acc[i][2]);                             \
            acc[i][3] = fmaf(x1, b1.w, acc[i][3]);                             \
            acc[i][0] = fmaf(x2, b2.x, acc[i][0]);                             \
            acc[i][1] = fmaf(x2, b2.y, acc[i][1]);                             \
            acc[i][2] = fmaf(x2, b2.z, acc[i][2]);                             \
            acc[i][3] = fmaf(x2, b2.w, acc[i][3]);                             \
            acc[i][0] = fmaf(x3, b3.x, acc[i][0]);                             \
            acc[i][1] = fmaf(x3, b3.y, acc[i][1]);                             \
            acc[i][2] = fmaf(x3, b3.z, acc[i][2]);                             \
            acc[i][3] = fmaf(x3, b3.w, acc[i][3]);                             \
        }                                                                      \
    }

// ===========================================================================
// Register-tiled GEMM: block = 64 rows x 64 cols, thread = 4x4 outputs.
// mode: 0 = bias, 2 = bias + BN + ReLU
// ===========================================================================
__global__ __launch_bounds__(256) void k_gemm_tile(const float* __restrict__ xin,
                                                   const float* __restrict__ W,
                                                   const float* __restrict__ bias,
                                                   const float* __restrict__ bng,
                                                   const float* __restrict__ bnb,
                                                   const float* __restrict__ bnm,
                                                   const float* __restrict__ bnv,
                                                   float* __restrict__ out,
                                                   int mode) {
    __shared__ float sW[4096];
    __shared__ float sX[64 * LDX];
    int tid = threadIdx.x;
    int row0 = blockIdx.x * 64;

    for (int i = tid; i < 1024; i += 256)
        ((float4*)sW)[i] = ((const float4*)W)[i];
    {
        int r = tid >> 2;          // 0..63
        int q = tid & 3;
        int row = row0 + r;
        float4* dst = (float4*)(sX + r * LDX);   // LDX*4 B = 272 = 16B-aligned
        if (row < N_NODES) {
            const float4* src = (const float4*)(xin + (size_t)row * DIM);
#pragma unroll
            for (int m = 0; m < 4; ++m) dst[q + m * 4] = src[q + m * 4];
        } else {
            float4 z = make_float4(0.f, 0.f, 0.f, 0.f);
#pragma unroll
            for (int m = 0; m < 4; ++m) dst[q + m * 4] = z;
        }
    }
    __syncthreads();

    int cq = tid & 15, rq = tid >> 4;
    int c0 = cq * 4, r0 = rq * 4;
    float acc[4][4];
#pragma unroll
    for (int i = 0; i < 4; ++i)
#pragma unroll
        for (int j = 0; j < 4; ++j) acc[i][j] = 0.f;

#pragma unroll 4
    for (int k4 = 0; k4 < 16; ++k4) GEMM_STEP(sX, sW)

    float4 bv = *(const float4*)&bias[c0];
    if (mode == 2) {
        float4 g = *(const float4*)&bng[c0];
        float4 bb = *(const float4*)&bnb[c0];
        float4 m = *(const float4*)&bnm[c0];
        float4 vv = *(const float4*)&bnv[c0];
        float A0 = g.x * rsqrtf(vv.x + BN_EPS);
        float A1 = g.y * rsqrtf(vv.y + BN_EPS);
        float A2 = g.z * rsqrtf(vv.z + BN_EPS);
        float A3 = g.w * rsqrtf(vv.w + BN_EPS);
        float B0 = (bv.x - m.x) * A0 + bb.x;
        float B1 = (bv.y - m.y) * A1 + bb.y;
        float B2 = (bv.z - m.z) * A2 + bb.z;
        float B3 = (bv.w - m.w) * A3 + bb.w;
#pragma unroll
        for (int i = 0; i < 4; ++i) {
            int row = row0 + r0 + i;
            if (row >= N_NODES) break;
            float4 o;
            o.x = fmaxf(0.f, fmaf(acc[i][0], A0, B0));
            o.y = fmaxf(0.f, fmaf(acc[i][1], A1, B1));
            o.z = fmaxf(0.f, fmaf(acc[i][2], A2, B2));
            o.w = fmaxf(0.f, fmaf(acc[i][3], A3, B3));
            *(float4*)(out + (size_t)row * DIM + c0) = o;
        }
    } else {
#pragma unroll
        for (int i = 0; i < 4; ++i) {
            int row = row0 + r0 + i;
            if (row >= N_NODES) break;
            float4 o;
            o.x = acc[i][0] + bv.x;
            o.y = acc[i][1] + bv.y;
            o.z = acc[i][2] + bv.z;
            o.w = acc[i][3] + bv.w;
            *(float4*)(out + (size_t)row * DIM + c0) = o;
        }
    }
}

// ===========================================================================
// Tail: out = tanh(x @ W3p + b3p) @ pW2 + pb2, tanh tile kept in LDS.
// ===========================================================================
__global__ __launch_bounds__(256) void k_tail(const float* __restrict__ xin,
                                              const float* __restrict__ W3p,
                                              const float* __restrict__ b3p,
                                              const float* __restrict__ pW2,
                                              const float* __restrict__ pb2,
                                              float* __restrict__ out) {
    __shared__ float sW1[4096];
    __shared__ float sW2[4096];
    __shared__ float sX[64 * LDX];
    int tid = threadIdx.x;
    int row0 = blockIdx.x * 64;

    for (int i = tid; i < 1024; i += 256) {
        ((float4*)sW1)[i] = ((const float4*)W3p)[i];
        ((float4*)sW2)[i] = ((const float4*)pW2)[i];
    }
    {
        int r = tid >> 2;
        int q = tid & 3;
        int row = row0 + r;
        float4* dst = (float4*)(sX + r * LDX);
        if (row < N_NODES) {
            const float4* src = (const float4*)(xin + (size_t)row * DIM);
#pragma unroll
            for (int m = 0; m < 4; ++m) dst[q + m * 4] = src[q + m * 4];
        } else {
            float4 z = make_float4(0.f, 0.f, 0.f, 0.f);
#pragma unroll
            for (int m = 0; m < 4; ++m) dst[q + m * 4] = z;
        }
    }
    __syncthreads();

    int cq = tid & 15, rq = tid >> 4;
    int c0 = cq * 4, r0 = rq * 4;
    float acc[4][4];

    // ---- GEMM 1: sX @ W3p ----
#pragma unroll
    for (int i = 0; i < 4; ++i)
#pragma unroll
        for (int j = 0; j < 4; ++j) acc[i][j] = 0.f;
#pragma unroll 4
    for (int k4 = 0; k4 < 16; ++k4) GEMM_STEP(sX, sW1)
    __syncthreads();   // all reads of sX done

    // tanh + bias, write H back into sX
    {
        float4 bv = *(const float4*)&b3p[c0];
#pragma unroll
        for (int i = 0; i < 4; ++i) {
            float4 h;
            h.x = tanhf(acc[i][0] + bv.x);
            h.y = tanhf(acc[i][1] + bv.y);
            h.z = tanhf(acc[i][2] + bv.z);
            h.w = tanhf(acc[i][3] + bv.w);
            *(float4*)&sX[(r0 + i) * LDX + c0] = h;
        }
    }
    __syncthreads();

    // ---- GEMM 2: sX @ pW2 ----
#pragma unroll
    for (int i = 0; i < 4; ++i)
#pragma unroll
        for (int j = 0; j < 4; ++j) acc[i][j] = 0.f;
#pragma unroll 4
    for (int k4 = 0; k4 < 16; ++k4) GEMM_STEP(sX, sW2)

    float4 bv = *(const float4*)&pb2[c0];
#pragma unroll
    for (int i = 0; i < 4; ++i) {
        int row = row0 + r0 + i;
        if (row >= N_NODES) break;
        float4 o;
        o.x = acc[i][0] + bv.x;
        o.y = acc[i][1] + bv.y;
        o.z = acc[i][2] + bv.z;
        o.w = acc[i][3] + bv.w;
        *(float4*)(out + (size_t)row * DIM + c0) = o;
    }
}

// ===========================================================================
extern "C" void kernel_launch(void* const* d_in, const int* in_sizes, int n_in,
                              void* d_out, int out_size, void* d_ws, size_t ws_size,
                              hipStream_t stream) {
    const float* x     = (const float*)d_in[0];
    const int*   ei    = (const int*)d_in[1];
    const float* W1    = (const float*)d_in[2];
    const float* b1    = (const float*)d_in[3];
    const float* W2    = (const float*)d_in[4];
    const float* b2    = (const float*)d_in[5];
    const float* W3    = (const float*)d_in[6];
    const float* b3    = (const float*)d_in[7];
    const float* bn1_g = (const float*)d_in[8];
    const float* bn1_b = (const float*)d_in[9];
    const float* bn1_m = (const float*)d_in[10];
    const float* bn1_v = (const float*)d_in[11];
    const float* bn2_g = (const float*)d_in[12];
    const float* bn2_b = (const float*)d_in[13];
    const float* bn2_m = (const float*)d_in[14];
    const float* bn2_v = (const float*)d_in[15];
    const float* pW1   = (const float*)d_in[16];
    const float* pb1   = (const float*)d_in[17];
    const float* pW2   = (const float*)d_in[18];
    const float* pb2   = (const float*)d_in[19];
    float* out = (float*)d_out;

    char* ws = (char*)d_ws;
    int*   deg      = (int*)ws;                      ws += 100352 * 4;
    int*   row_off  = (int*)ws;                      ws += 100352 * 4;
    int*   cursor   = (int*)ws;                      ws += 100352 * 4;
    int*   bsums    = (int*)ws;                      ws += 128 * 4;
    int2*  edges    = (int2*)ws;                     ws += (size_t)1600000 * 8;  // padded CSR
    float* dinv     = (float*)ws;                    ws += 100352 * 4;
    float* W3p      = (float*)ws;                    ws += 4096 * 4;
    float* b3p      = (float*)ws;                    ws += 64 * 4;
    float* bufA     = (float*)ws;                    ws += (size_t)N_NODES * DIM * 4;
    float* bufB     = (float*)ws;

    const int blk = 256;
    int gN    = (N_NODES + blk - 1) / blk;       // 391
    int gE    = (N_EDGES + blk - 1) / blk;       // 3125
    int gScan = 98;
    int gAgg  = N_NODES / 4;                     // 25000 (exact)
    int gTile = (N_NODES + 63) / 64;             // 1563

    // ---- CSR build (once, reused by all 3 layers) ----
    k_zero_deg<<<gN, blk, 0, stream>>>(deg);
    k_count<<<gE, blk, 0, stream>>>(ei + N_EDGES, deg);
    k_scan1<<<gScan, blk, 0, stream>>>(deg, row_off, bsums);
    k_scan2<<<1, 128, 0, stream>>>(bsums);
    k_scan3<<<gScan, blk, 0, stream>>>(deg, row_off, cursor, dinv, bsums);
    k_build<<<gE, blk, 0, stream>>>(ei, dinv, cursor, edges);
    k_pad<<<gN, blk, 0, stream>>>(deg, row_off, edges);
    k_fuse_w3<<<1, blk, 0, stream>>>(W3, b3, pW1, pb1, W3p, b3p);

    // ---- layer 1 ----
    k_aggregate<<<gAgg, blk, 0, stream>>>(x, row_off, deg, edges, dinv, bufA);
    k_gemm_tile<<<gTile, blk, 0, stream>>>(bufA, W1, b1, bn1_g, bn1_b, bn1_m, bn1_v, bufB, 2);

    // ---- layer 2 ----
    k_aggregate<<<gAgg, blk, 0, stream>>>(bufB, row_off, deg, edges, dinv, bufA);
    k_gemm_tile<<<gTile, blk, 0, stream>>>(bufA, W2, b2, bn2_g, bn2_b, bn2_m, bn2_v, bufB, 2);

    // ---- layer 3 + fused predictor ----
    k_aggregate<<<gAgg, blk, 0, stream>>>(bufB, row_off, deg, edges, dinv, bufA);
    k_tail<<<gTile, blk, 0, stream>>>(bufA, W3p, b3p, pW2, pb2, out);
}

// Round 9
// 382.821 us; speedup vs baseline: 1.2485x; 1.0247x over previous
//
#include <hip/hip_runtime.h>
#include <hip/hip_fp16.h>

#define N_NODES 100000
#define N_EDGES 800000
#define DIM 64
#define BN_EPS 1e-5f
#define LDX 68   // sX row stride (floats): 16B-aligned, 2-way banks (free)
#define EDGE_CAP 1600000

// ===========================================================================
// CSR build. Padding to x8 via pre-zeroed edge array: dummy edge {src=0,w=0}
// contributes nothing. Segment order across nodes is irrelevant -> atomic-base
// scan (one kernel) instead of ordered 3-kernel scan.
// ===========================================================================

__global__ __launch_bounds__(256) void k_count(const int* __restrict__ dst,
                                               int* __restrict__ deg) {
    int e = blockIdx.x * blockDim.x + threadIdx.x;
    if (e < N_EDGES) atomicAdd(&deg[dst[e]], 1);
}

// 98 blocks x 256 threads x 4 elems = 100352 >= N.
// Block-local scan of padded degrees + atomicAdd global base.
// Writes row_off, cursor (=row_off), dinv.
__global__ __launch_bounds__(256) void k_scan(const int* __restrict__ deg,
                                              int* __restrict__ row_off,
                                              int* __restrict__ cursor,
                                              float* __restrict__ dinv,
                                              int* __restrict__ gcount) {
    __shared__ int sdata[256];
    __shared__ int sbase;
    int tid = threadIdx.x;
    int base = blockIdx.x * 1024 + tid * 4;
    int4 d = make_int4(0, 0, 0, 0);
    int4 v = make_int4(0, 0, 0, 0);
    if (base < N_NODES) {
        d = *(const int4*)(deg + base);   // N % 4 == 0
        v.x = (d.x + 7) & ~7;
        v.y = (d.y + 7) & ~7;
        v.z = (d.z + 7) & ~7;
        v.w = (d.w + 7) & ~7;
    }
    int tsum = v.x + v.y + v.z + v.w;
    sdata[tid] = tsum;
    __syncthreads();
    for (int off = 1; off < 256; off <<= 1) {
        int t = (tid >= off) ? sdata[tid - off] : 0;
        __syncthreads();
        sdata[tid] += t;
        __syncthreads();
    }
    if (tid == 255) sbase = atomicAdd(gcount, sdata[255]);
    __syncthreads();
    if (base >= N_NODES) return;
    int excl = sdata[tid] - tsum + sbase;
    int4 o;
    o.x = excl;
    o.y = o.x + v.x;
    o.z = o.y + v.y;
    o.w = o.z + v.z;
    *(int4*)(row_off + base) = o;
    *(int4*)(cursor + base) = o;
    float4 di;
    di.x = rsqrtf((float)(d.x + 1));
    di.y = rsqrtf((float)(d.y + 1));
    di.z = rsqrtf((float)(d.z + 1));
    di.w = rsqrtf((float)(d.w + 1));
    *(float4*)(dinv + base) = di;
}

__global__ __launch_bounds__(256) void k_build(const int* __restrict__ ei,
                                               const float* __restrict__ dinv,
                                               int* __restrict__ cursor,
                                               int2* __restrict__ edges) {
    int e = blockIdx.x * blockDim.x + threadIdx.x;
    if (e >= N_EDGES) return;
    int s = ei[e];
    int d = ei[N_EDGES + e];
    int pos = atomicAdd(&cursor[d], 1);
    edges[pos] = make_int2(s, __float_as_int(dinv[s] * dinv[d]));
}

// ===========================================================================
// x (f32) -> xh (fp16), packed uint2 stores
// ===========================================================================
__global__ __launch_bounds__(256) void k_tohalf(const float* __restrict__ x,
                                                __half* __restrict__ xh) {
    int idx = blockIdx.x * blockDim.x + threadIdx.x;   // 1.6M float4s
    float4 v = ((const float4*)x)[idx];
    unsigned int u0 = __half_as_ushort(__float2half(v.x));
    unsigned int u1 = __half_as_ushort(__float2half(v.y));
    unsigned int u2 = __half_as_ushort(__float2half(v.z));
    unsigned int u3 = __half_as_ushort(__float2half(v.w));
    ((uint2*)xh)[idx] = make_uint2(u0 | (u1 << 16), u2 | (u3 << 16));
}

// ===========================================================================
// Tail algebra: W3p = W3 @ pW1, b3p = b3 @ pW1 + pb1  (one block)
// ===========================================================================
__global__ __launch_bounds__(256) void k_fuse_w3(const float* __restrict__ W3,
                                                 const float* __restrict__ b3,
                                                 const float* __restrict__ pW1,
                                                 const float* __restrict__ pb1,
                                                 float* __restrict__ W3p,
                                                 float* __restrict__ b3p) {
    int tid = threadIdx.x;
    int c = tid & 63;
    int kbase = (tid >> 6) * 16;
    for (int k = kbase; k < kbase + 16; ++k) {
        float acc = 0.f;
#pragma unroll 8
        for (int j = 0; j < 64; ++j)
            acc = fmaf(W3[k * 64 + j], pW1[j * 64 + c], acc);
        W3p[k * 64 + c] = acc;
    }
    if (tid < 64) {
        float acc = pb1[c];
#pragma unroll 8
        for (int j = 0; j < 64; ++j)
            acc = fmaf(b3[j], pW1[j * 64 + c], acc);
        b3p[c] = acc;
    }
}

// ===========================================================================
// Aggregation over fp16 features: one wave per node, lane = column.
// CSR segments padded to x8 (pads are {0,0}: contribute 0).
// out[n] (f32) = dinv[n]^2*xh[n] + sum_e w_e*xh[src_e]
// ===========================================================================
__global__ __launch_bounds__(256) void k_aggregate(const __half* __restrict__ xin,
                                                   const int* __restrict__ row_off,
                                                   const int* __restrict__ deg,
                                                   const int2* __restrict__ edges,
                                                   const float* __restrict__ dinv,
                                                   float* __restrict__ out) {
    int lane = threadIdx.x & 63;
    int node = blockIdx.x * 4 + (threadIdx.x >> 6);   // grid = 25000 exact
    float di = dinv[node];
    float acc = __half2float(xin[(size_t)node * DIM + lane]) * (di * di);
    int beg = __builtin_amdgcn_readfirstlane(row_off[node]);
    int lenp = (__builtin_amdgcn_readfirstlane(deg[node]) + 7) & ~7;
    int end = beg + lenp;
    for (int k = beg; k < end; k += 8) {
        int2 e0 = edges[k + 0];
        int2 e1 = edges[k + 1];
        int2 e2 = edges[k + 2];
        int2 e3 = edges[k + 3];
        int2 e4 = edges[k + 4];
        int2 e5 = edges[k + 5];
        int2 e6 = edges[k + 6];
        int2 e7 = edges[k + 7];
        float v0 = __half2float(xin[(size_t)e0.x * DIM + lane]);
        float v1 = __half2float(xin[(size_t)e1.x * DIM + lane]);
        float v2 = __half2float(xin[(size_t)e2.x * DIM + lane]);
        float v3 = __half2float(xin[(size_t)e3.x * DIM + lane]);
        float v4 = __half2float(xin[(size_t)e4.x * DIM + lane]);
        float v5 = __half2float(xin[(size_t)e5.x * DIM + lane]);
        float v6 = __half2float(xin[(size_t)e6.x * DIM + lane]);
        float v7 = __half2float(xin[(size_t)e7.x * DIM + lane]);
        acc = fmaf(__int_as_float(e0.y), v0, acc);
        acc = fmaf(__int_as_float(e1.y), v1, acc);
        acc = fmaf(__int_as_float(e2.y), v2, acc);
        acc = fmaf(__int_as_float(e3.y), v3, acc);
        acc = fmaf(__int_as_float(e4.y), v4, acc);
        acc = fmaf(__int_as_float(e5.y), v5, acc);
        acc = fmaf(__int_as_float(e6.y), v6, acc);
        acc = fmaf(__int_as_float(e7.y), v7, acc);
    }
    out[(size_t)node * DIM + lane] = acc;
}

// 64 FMAs of a 4-row x 4-col x 4-k outer-product step (sX stride = LDX)
#define GEMM_STEP(SX, SW)                                                      \
    {                                                                          \
        float4 a0 = *(const float4*)&SX[(r0 + 0) * LDX + k4 * 4];              \
        float4 a1 = *(const float4*)&SX[(r0 + 1) * LDX + k4 * 4];              \
        float4 a2 = *(const float4*)&SX[(r0 + 2) * LDX + k4 * 4];              \
        float4 a3 = *(const float4*)&SX[(r0 + 3) * LDX + k4 * 4];              \
        float4 b0 = *(const float4*)&SW[(k4 * 4 + 0) * 64 + c0];               \
        float4 b1 = *(const float4*)&SW[(k4 * 4 + 1) * 64 + c0];               \
        float4 b2 = *(const float4*)&SW[(k4 * 4 + 2) * 64 + c0];               \
        float4 b3 = *(const float4*)&SW[(k4 * 4 + 3) * 64 + c0];               \
        const float* ap[4] = {&a0.x, &a1.x, &a2.x, &a3.x};                     \
        _Pragma("unroll") for (int i = 0; i < 4; ++i) {                        \
            float x0 = ap[i][0], x1 = ap[i][1], x2 = ap[i][2], x3 = ap[i][3];  \
            acc[i][0] = fmaf(x0, b0.x, acc[i][0]);                             \
            acc[i][1] = fmaf(x0, b0.y, acc[i][1]);                             \
            acc[i][2] = fmaf(x0, b0.z, acc[i][2]);                             \
            acc[i][3] = fmaf(x0, b0.w, acc[i][3]);                             \
            acc[i][0] = fmaf(x1, b1.x, acc[i][0]);                             \
            acc[i][1] = fmaf(x1, b1.y, acc[i][1]);                             \
            acc[i][2] = fmaf(x1, b1.z, acc[i][2]);                             \
            acc[i][3] = fmaf(x1, b1.w, acc[i][3]);                             \
            acc[i][0] = fmaf(x2, b2.x, acc[i][0]);                             \
            acc[i][1] = fmaf(x2, b2.y, acc[i][1]);                             \
            acc[i][2] = fmaf(x2, b2.z, acc[i][2]);                             \
            acc[i][3] = fmaf(x2, b2.w, acc[i][3]);                             \
            acc[i][0] = fmaf(x3, b3.x, acc[i][0]);                             \
            acc[i][1] = fmaf(x3, b3.y, acc[i][1]);                             \
            acc[i][2] = fmaf(x3, b3.z, acc[i][2]);                             \
            acc[i][3] = fmaf(x3, b3.w, acc[i][3]);                             \
        }                                                                      \
    }

// ===========================================================================
// Register-tiled GEMM + BN + ReLU, fp16 output (feeds the next gather).
// Block = 64 rows x 64 cols, thread = 4x4 outputs.
// ===========================================================================
__global__ __launch_bounds__(256) void k_gemm_bn_h(const float* __restrict__ xin,
                                                   const float* __restrict__ W,
                                                   const float* __restrict__ bias,
                                                   const float* __restrict__ bng,
                                                   const float* __restrict__ bnb,
                                                   const float* __restrict__ bnm,
                                                   const float* __restrict__ bnv,
                                                   __half* __restrict__ out) {
    __shared__ float sW[4096];
    __shared__ float sX[64 * LDX];
    int tid = threadIdx.x;
    int row0 = blockIdx.x * 64;

    for (int i = tid; i < 1024; i += 256)
        ((float4*)sW)[i] = ((const float4*)W)[i];
    {
        int r = tid >> 2;
        int q = tid & 3;
        int row = row0 + r;
        float4* dst = (float4*)(sX + r * LDX);
        if (row < N_NODES) {
            const float4* src = (const float4*)(xin + (size_t)row * DIM);
#pragma unroll
            for (int m = 0; m < 4; ++m) dst[q + m * 4] = src[q + m * 4];
        } else {
            float4 z = make_float4(0.f, 0.f, 0.f, 0.f);
#pragma unroll
            for (int m = 0; m < 4; ++m) dst[q + m * 4] = z;
        }
    }
    __syncthreads();

    int cq = tid & 15, rq = tid >> 4;
    int c0 = cq * 4, r0 = rq * 4;
    float acc[4][4];
#pragma unroll
    for (int i = 0; i < 4; ++i)
#pragma unroll
        for (int j = 0; j < 4; ++j) acc[i][j] = 0.f;

#pragma unroll 4
    for (int k4 = 0; k4 < 16; ++k4) GEMM_STEP(sX, sW)

    float4 bv = *(const float4*)&bias[c0];
    float4 g = *(const float4*)&bng[c0];
    float4 bb = *(const float4*)&bnb[c0];
    float4 m = *(const float4*)&bnm[c0];
    float4 vv = *(const float4*)&bnv[c0];
    float A0 = g.x * rsqrtf(vv.x + BN_EPS);
    float A1 = g.y * rsqrtf(vv.y + BN_EPS);
    float A2 = g.z * rsqrtf(vv.z + BN_EPS);
    float A3 = g.w * rsqrtf(vv.w + BN_EPS);
    float B0 = (bv.x - m.x) * A0 + bb.x;
    float B1 = (bv.y - m.y) * A1 + bb.y;
    float B2 = (bv.z - m.z) * A2 + bb.z;
    float B3 = (bv.w - m.w) * A3 + bb.w;
#pragma unroll
    for (int i = 0; i < 4; ++i) {
        int row = row0 + r0 + i;
        if (row >= N_NODES) break;
        unsigned int u0 = __half_as_ushort(__float2half(fmaxf(0.f, fmaf(acc[i][0], A0, B0))));
        unsigned int u1 = __half_as_ushort(__float2half(fmaxf(0.f, fmaf(acc[i][1], A1, B1))));
        unsigned int u2 = __half_as_ushort(__float2half(fmaxf(0.f, fmaf(acc[i][2], A2, B2))));
        unsigned int u3 = __half_as_ushort(__float2half(fmaxf(0.f, fmaf(acc[i][3], A3, B3))));
        *(uint2*)(out + (size_t)row * DIM + c0) = make_uint2(u0 | (u1 << 16), u2 | (u3 << 16));
    }
}

// ===========================================================================
// Tail: out = tanh(x @ W3p + b3p) @ pW2 + pb2, tanh tile kept in LDS.
// f32 in, f32 out.
// ===========================================================================
__global__ __launch_bounds__(256) void k_tail(const float* __restrict__ xin,
                                              const float* __restrict__ W3p,
                                              const float* __restrict__ b3p,
                                              const float* __restrict__ pW2,
                                              const float* __restrict__ pb2,
                                              float* __restrict__ out) {
    __shared__ float sW1[4096];
    __shared__ float sW2[4096];
    __shared__ float sX[64 * LDX];
    int tid = threadIdx.x;
    int row0 = blockIdx.x * 64;

    for (int i = tid; i < 1024; i += 256) {
        ((float4*)sW1)[i] = ((const float4*)W3p)[i];
        ((float4*)sW2)[i] = ((const float4*)pW2)[i];
    }
    {
        int r = tid >> 2;
        int q = tid & 3;
        int row = row0 + r;
        float4* dst = (float4*)(sX + r * LDX);
        if (row < N_NODES) {
            const float4* src = (const float4*)(xin + (size_t)row * DIM);
#pragma unroll
            for (int m = 0; m < 4; ++m) dst[q + m * 4] = src[q + m * 4];
        } else {
            float4 z = make_float4(0.f, 0.f, 0.f, 0.f);
#pragma unroll
            for (int m = 0; m < 4; ++m) dst[q + m * 4] = z;
        }
    }
    __syncthreads();

    int cq = tid & 15, rq = tid >> 4;
    int c0 = cq * 4, r0 = rq * 4;
    float acc[4][4];

    // ---- GEMM 1: sX @ W3p ----
#pragma unroll
    for (int i = 0; i < 4; ++i)
#pragma unroll
        for (int j = 0; j < 4; ++j) acc[i][j] = 0.f;
#pragma unroll 4
    for (int k4 = 0; k4 < 16; ++k4) GEMM_STEP(sX, sW1)
    __syncthreads();

    {
        float4 bv = *(const float4*)&b3p[c0];
#pragma unroll
        for (int i = 0; i < 4; ++i) {
            float4 h;
            h.x = tanhf(acc[i][0] + bv.x);
            h.y = tanhf(acc[i][1] + bv.y);
            h.z = tanhf(acc[i][2] + bv.z);
            h.w = tanhf(acc[i][3] + bv.w);
            *(float4*)&sX[(r0 + i) * LDX + c0] = h;
        }
    }
    __syncthreads();

    // ---- GEMM 2: sX @ pW2 ----
#pragma unroll
    for (int i = 0; i < 4; ++i)
#pragma unroll
        for (int j = 0; j < 4; ++j) acc[i][j] = 0.f;
#pragma unroll 4
    for (int k4 = 0; k4 < 16; ++k4) GEMM_STEP(sX, sW2)

    float4 bv = *(const float4*)&pb2[c0];
#pragma unroll
    for (int i = 0; i < 4; ++i) {
        int row = row0 + r0 + i;
        if (row >= N_NODES) break;
        float4 o;
        o.x = acc[i][0] + bv.x;
        o.y = acc[i][1] + bv.y;
        o.z = acc[i][2] + bv.z;
        o.w = acc[i][3] + bv.w;
        *(float4*)(out + (size_t)row * DIM + c0) = o;
    }
}

// ===========================================================================
extern "C" void kernel_launch(void* const* d_in, const int* in_sizes, int n_in,
                              void* d_out, int out_size, void* d_ws, size_t ws_size,
                              hipStream_t stream) {
    const float* x     = (const float*)d_in[0];
    const int*   ei    = (const int*)d_in[1];
    const float* W1    = (const float*)d_in[2];
    const float* b1    = (const float*)d_in[3];
    const float* W2    = (const float*)d_in[4];
    const float* b2    = (const float*)d_in[5];
    const float* W3    = (const float*)d_in[6];
    const float* b3    = (const float*)d_in[7];
    const float* bn1_g = (const float*)d_in[8];
    const float* bn1_b = (const float*)d_in[9];
    const float* bn1_m = (const float*)d_in[10];
    const float* bn1_v = (const float*)d_in[11];
    const float* bn2_g = (const float*)d_in[12];
    const float* bn2_b = (const float*)d_in[13];
    const float* bn2_m = (const float*)d_in[14];
    const float* bn2_v = (const float*)d_in[15];
    const float* pW1   = (const float*)d_in[16];
    const float* pb1   = (const float*)d_in[17];
    const float* pW2   = (const float*)d_in[18];
    const float* pb2   = (const float*)d_in[19];
    float* out = (float*)d_out;

    char* ws = (char*)d_ws;
    int*   deg      = (int*)ws;                      ws += 100352 * 4;
    int*   gcount   = (int*)ws;                      ws += 4 * 4;        // zeroed with deg
    int*   row_off  = (int*)ws;                      ws += 100352 * 4;
    int*   cursor   = (int*)ws;                      ws += 100352 * 4;
    int2*  edges    = (int2*)ws;                     ws += (size_t)EDGE_CAP * 8;
    float* dinv     = (float*)ws;                    ws += 100352 * 4;
    float* W3p      = (float*)ws;                    ws += 4096 * 4;
    float* b3p      = (float*)ws;                    ws += 64 * 4;
    __half* xh      = (__half*)ws;                   ws += (size_t)N_NODES * DIM * 2;
    __half* hbuf    = (__half*)ws;                   ws += (size_t)N_NODES * DIM * 2;
    float* bufA     = (float*)ws;                    ws += (size_t)N_NODES * DIM * 4;

    const int blk = 256;
    int gE    = (N_EDGES + blk - 1) / blk;       // 3125
    int gScan = 98;
    int gCvt  = N_NODES * 16 / blk;              // 6250 (N*64/4 float4s)
    int gAgg  = N_NODES / 4;                     // 25000 (exact)
    int gTile = (N_NODES + 63) / 64;             // 1563

    // ---- CSR build (once, reused by all 3 layers) ----
    hipMemsetAsync(deg, 0, (100352 + 4) * 4, stream);          // deg + gcount
    hipMemsetAsync(edges, 0, (size_t)EDGE_CAP * 8, stream);    // pads = {0, w=0}
    k_tohalf<<<gCvt, blk, 0, stream>>>(x, xh);
    k_count<<<gE, blk, 0, stream>>>(ei + N_EDGES, deg);
    k_scan<<<gScan, blk, 0, stream>>>(deg, row_off, cursor, dinv, gcount);
    k_build<<<gE, blk, 0, stream>>>(ei, dinv, cursor, edges);
    k_fuse_w3<<<1, blk, 0, stream>>>(W3, b3, pW1, pb1, W3p, b3p);

    // ---- layer 1 ----
    k_aggregate<<<gAgg, blk, 0, stream>>>(xh, row_off, deg, edges, dinv, bufA);
    k_gemm_bn_h<<<gTile, blk, 0, stream>>>(bufA, W1, b1, bn1_g, bn1_b, bn1_m, bn1_v, hbuf);

    // ---- layer 2 ----
    k_aggregate<<<gAgg, blk, 0, stream>>>(hbuf, row_off, deg, edges, dinv, bufA);
    k_gemm_bn_h<<<gTile, blk, 0, stream>>>(bufA, W2, b2, bn2_g, bn2_b, bn2_m, bn2_v, hbuf);

    // ---- layer 3 + fused predictor ----
    k_aggregate<<<gAgg, blk, 0, stream>>>(hbuf, row_off, deg, edges, dinv, bufA);
    k_tail<<<gTile, blk, 0, stream>>>(bufA, W3p, b3p, pW2, pb2, out);
}

// Round 10
// 372.928 us; speedup vs baseline: 1.2816x; 1.0265x over previous
//
#include <hip/hip_runtime.h>
#include <hip/hip_fp16.h>

#define N_NODES 100000
#define N_EDGES 800000
#define DIM 64
#define BN_EPS 1e-5f
#define LDX 68   // sX row stride (floats): 16B-aligned, 2-way banks (free)
#define EDGE_CAP 1600000

// ===========================================================================
// Merged: x (f32) -> xh (fp16) conversion  +  in-degree count.
// 6250 blocks x 256: idx < 1.6M does one float4->uint2 cvt; idx < 800k counts.
// ===========================================================================
__global__ __launch_bounds__(256) void k_cvt_count(const float* __restrict__ x,
                                                   __half* __restrict__ xh,
                                                   const int* __restrict__ dst,
                                                   int* __restrict__ deg) {
    int idx = blockIdx.x * blockDim.x + threadIdx.x;
    if (idx < 1600000) {
        float4 v = ((const float4*)x)[idx];
        unsigned int u0 = __half_as_ushort(__float2half(v.x));
        unsigned int u1 = __half_as_ushort(__float2half(v.y));
        unsigned int u2 = __half_as_ushort(__float2half(v.z));
        unsigned int u3 = __half_as_ushort(__float2half(v.w));
        ((uint2*)xh)[idx] = make_uint2(u0 | (u1 << 16), u2 | (u3 << 16));
    }
    if (idx < N_EDGES) atomicAdd(&deg[dst[idx]], 1);
}

// ===========================================================================
// Merged scan + tail-weight algebra.
// Blocks 0..97: block-local scan of padded degrees + atomic global base;
// writes row_off, cursor, dinv. Block 98: W3p = W3@pW1, b3p = b3@pW1+pb1.
// ===========================================================================
__global__ __launch_bounds__(256) void k_scan_fuse(const int* __restrict__ deg,
                                                   int* __restrict__ row_off,
                                                   int* __restrict__ cursor,
                                                   float* __restrict__ dinv,
                                                   int* __restrict__ gcount,
                                                   const float* __restrict__ W3,
                                                   const float* __restrict__ b3,
                                                   const float* __restrict__ pW1,
                                                   const float* __restrict__ pb1,
                                                   float* __restrict__ W3p,
                                                   float* __restrict__ b3p) {
    int tid = threadIdx.x;
    if (blockIdx.x == 98) {
        int c = tid & 63;
        int kbase = (tid >> 6) * 16;
        for (int k = kbase; k < kbase + 16; ++k) {
            float acc = 0.f;
#pragma unroll 8
            for (int j = 0; j < 64; ++j)
                acc = fmaf(W3[k * 64 + j], pW1[j * 64 + c], acc);
            W3p[k * 64 + c] = acc;
        }
        if (tid < 64) {
            float acc = pb1[c];
#pragma unroll 8
            for (int j = 0; j < 64; ++j)
                acc = fmaf(b3[j], pW1[j * 64 + c], acc);
            b3p[c] = acc;
        }
        return;
    }
    __shared__ int sdata[256];
    __shared__ int sbase;
    int base = blockIdx.x * 1024 + tid * 4;
    int4 d = make_int4(0, 0, 0, 0);
    int4 v = make_int4(0, 0, 0, 0);
    if (base < N_NODES) {
        d = *(const int4*)(deg + base);   // N % 4 == 0
        v.x = (d.x + 7) & ~7;
        v.y = (d.y + 7) & ~7;
        v.z = (d.z + 7) & ~7;
        v.w = (d.w + 7) & ~7;
    }
    int tsum = v.x + v.y + v.z + v.w;
    sdata[tid] = tsum;
    __syncthreads();
    for (int off = 1; off < 256; off <<= 1) {
        int t = (tid >= off) ? sdata[tid - off] : 0;
        __syncthreads();
        sdata[tid] += t;
        __syncthreads();
    }
    if (tid == 255) sbase = atomicAdd(gcount, sdata[255]);
    __syncthreads();
    if (base >= N_NODES) return;
    int excl = sdata[tid] - tsum + sbase;
    int4 o;
    o.x = excl;
    o.y = o.x + v.x;
    o.z = o.y + v.y;
    o.w = o.z + v.z;
    *(int4*)(row_off + base) = o;
    *(int4*)(cursor + base) = o;
    float4 di;
    di.x = rsqrtf((float)(d.x + 1));
    di.y = rsqrtf((float)(d.y + 1));
    di.z = rsqrtf((float)(d.z + 1));
    di.w = rsqrtf((float)(d.w + 1));
    *(float4*)(dinv + base) = di;
}

__global__ __launch_bounds__(256) void k_build(const int* __restrict__ ei,
                                               const float* __restrict__ dinv,
                                               int* __restrict__ cursor,
                                               int2* __restrict__ edges) {
    int e = blockIdx.x * blockDim.x + threadIdx.x;
    if (e >= N_EDGES) return;
    int s = ei[e];
    int d = ei[N_EDGES + e];
    int pos = atomicAdd(&cursor[d], 1);
    edges[pos] = make_int2(s, __float_as_int(dinv[s] * dinv[d]));
}

// ===========================================================================
// Aggregation over fp16 features, fp16 output: one wave per node, lane = col.
// CSR segments padded to x8 (pads are {0,0}: contribute 0).
// ===========================================================================
__global__ __launch_bounds__(256) void k_aggregate(const __half* __restrict__ xin,
                                                   const int* __restrict__ row_off,
                                                   const int* __restrict__ deg,
                                                   const int2* __restrict__ edges,
                                                   const float* __restrict__ dinv,
                                                   __half* __restrict__ out) {
    int lane = threadIdx.x & 63;
    int node = blockIdx.x * 4 + (threadIdx.x >> 6);   // grid = 25000 exact
    float di = dinv[node];
    float acc = __half2float(xin[(size_t)node * DIM + lane]) * (di * di);
    int beg = __builtin_amdgcn_readfirstlane(row_off[node]);
    int lenp = (__builtin_amdgcn_readfirstlane(deg[node]) + 7) & ~7;
    int end = beg + lenp;
    for (int k = beg; k < end; k += 8) {
        int2 e0 = edges[k + 0];
        int2 e1 = edges[k + 1];
        int2 e2 = edges[k + 2];
        int2 e3 = edges[k + 3];
        int2 e4 = edges[k + 4];
        int2 e5 = edges[k + 5];
        int2 e6 = edges[k + 6];
        int2 e7 = edges[k + 7];
        float v0 = __half2float(xin[(size_t)e0.x * DIM + lane]);
        float v1 = __half2float(xin[(size_t)e1.x * DIM + lane]);
        float v2 = __half2float(xin[(size_t)e2.x * DIM + lane]);
        float v3 = __half2float(xin[(size_t)e3.x * DIM + lane]);
        float v4 = __half2float(xin[(size_t)e4.x * DIM + lane]);
        float v5 = __half2float(xin[(size_t)e5.x * DIM + lane]);
        float v6 = __half2float(xin[(size_t)e6.x * DIM + lane]);
        float v7 = __half2float(xin[(size_t)e7.x * DIM + lane]);
        acc = fmaf(__int_as_float(e0.y), v0, acc);
        acc = fmaf(__int_as_float(e1.y), v1, acc);
        acc = fmaf(__int_as_float(e2.y), v2, acc);
        acc = fmaf(__int_as_float(e3.y), v3, acc);
        acc = fmaf(__int_as_float(e4.y), v4, acc);
        acc = fmaf(__int_as_float(e5.y), v5, acc);
        acc = fmaf(__int_as_float(e6.y), v6, acc);
        acc = fmaf(__int_as_float(e7.y), v7, acc);
    }
    out[(size_t)node * DIM + lane] = __float2half(acc);
}

// 64 FMAs of a 4-row x 4-col x 4-k outer-product step (sX stride = LDX)
#define GEMM_STEP(SX, SW)                                                      \
    {                                                                          \
        float4 a0 = *(const float4*)&SX[(r0 + 0) * LDX + k4 * 4];              \
        float4 a1 = *(const float4*)&SX[(r0 + 1) * LDX + k4 * 4];              \
        float4 a2 = *(const float4*)&SX[(r0 + 2) * LDX + k4 * 4];              \
        float4 a3 = *(const float4*)&SX[(r0 + 3) * LDX + k4 * 4];              \
        float4 b0 = *(const float4*)&SW[(k4 * 4 + 0) * 64 + c0];               \
        float4 b1 = *(const float4*)&SW[(k4 * 4 + 1) * 64 + c0];               \
        float4 b2 = *(const float4*)&SW[(k4 * 4 + 2) * 64 + c0];               \
        float4 b3 = *(const float4*)&SW[(k4 * 4 + 3) * 64 + c0];               \
        const float* ap[4] = {&a0.x, &a1.x, &a2.x, &a3.x};                     \
        _Pragma("unroll") for (int i = 0; i < 4; ++i) {                        \
            float x0 = ap[i][0], x1 = ap[i][1], x2 = ap[i][2], x3 = ap[i][3];  \
            acc[i][0] = fmaf(x0, b0.x, acc[i][0]);                             \
            acc[i][1] = fmaf(x0, b0.y, acc[i][1]);                             \
            acc[i][2] = fmaf(x0, b0.z, acc[i][2]);                             \
            acc[i][3] = fmaf(x0, b0.w, acc[i][3]);                             \
            acc[i][0] = fmaf(x1, b1.x, acc[i][0]);                             \
            acc[i][1] = fmaf(x1, b1.y, acc[i][1]);                             \
            acc[i][2] = fmaf(x1, b1.z, acc[i][2]);                             \
            acc[i][3] = fmaf(x1, b1.w, acc[i][3]);                             \
            acc[i][0] = fmaf(x2, b2.x, acc[i][0]);                             \
            acc[i][1] = fmaf(x2, b2.y, acc[i][1]);                             \
            acc[i][2] = fmaf(x2, b2.z, acc[i][2]);                             \
            acc[i][3] = fmaf(x2, b2.w, acc[i][3]);                             \
            acc[i][0] = fmaf(x3, b3.x, acc[i][0]);                             \
            acc[i][1] = fmaf(x3, b3.y, acc[i][1]);                             \
            acc[i][2] = fmaf(x3, b3.z, acc[i][2]);                             \
            acc[i][3] = fmaf(x3, b3.w, acc[i][3]);                             \
        }                                                                      \
    }

// stage one 64-row fp16 tile into fp32 LDS (thread r=tid>>2, q=tid&3)
#define STAGE_H2F(SRCPTR, SXPTR)                                               \
    {                                                                          \
        int r = tid >> 2;                                                      \
        int q = tid & 3;                                                       \
        int row = row0 + r;                                                    \
        float4* dst = (float4*)(SXPTR + r * LDX);                              \
        if (row < N_NODES) {                                                   \
            const uint2* src = (const uint2*)(SRCPTR + (size_t)row * DIM);     \
            _Pragma("unroll") for (int m = 0; m < 4; ++m) {                    \
                uint2 u = src[q + m * 4];                                      \
                float4 f;                                                      \
                f.x = __half2float(__ushort_as_half((unsigned short)(u.x & 0xffff)));       \
                f.y = __half2float(__ushort_as_half((unsigned short)(u.x >> 16)));          \
                f.z = __half2float(__ushort_as_half((unsigned short)(u.y & 0xffff)));       \
                f.w = __half2float(__ushort_as_half((unsigned short)(u.y >> 16)));          \
                dst[q + m * 4] = f;                                            \
            }                                                                  \
        } else {                                                               \
            float4 z = make_float4(0.f, 0.f, 0.f, 0.f);                        \
            _Pragma("unroll") for (int m = 0; m < 4; ++m) dst[q + m * 4] = z;  \
        }                                                                      \
    }

// ===========================================================================
// Register-tiled GEMM + BN + ReLU: fp16 in, fp16 out, fp32 math.
// Block = 64 rows x 64 cols, thread = 4x4 outputs.
// ===========================================================================
__global__ __launch_bounds__(256) void k_gemm_bn_h(const __half* __restrict__ xin,
                                                   const float* __restrict__ W,
                                                   const float* __restrict__ bias,
                                                   const float* __restrict__ bng,
                                                   const float* __restrict__ bnb,
                                                   const float* __restrict__ bnm,
                                                   const float* __restrict__ bnv,
                                                   __half* __restrict__ out) {
    __shared__ float sW[4096];
    __shared__ float sX[64 * LDX];
    int tid = threadIdx.x;
    int row0 = blockIdx.x * 64;

    for (int i = tid; i < 1024; i += 256)
        ((float4*)sW)[i] = ((const float4*)W)[i];
    STAGE_H2F(xin, sX)
    __syncthreads();

    int cq = tid & 15, rq = tid >> 4;
    int c0 = cq * 4, r0 = rq * 4;
    float acc[4][4];
#pragma unroll
    for (int i = 0; i < 4; ++i)
#pragma unroll
        for (int j = 0; j < 4; ++j) acc[i][j] = 0.f;

#pragma unroll 4
    for (int k4 = 0; k4 < 16; ++k4) GEMM_STEP(sX, sW)

    float4 bv = *(const float4*)&bias[c0];
    float4 g = *(const float4*)&bng[c0];
    float4 bb = *(const float4*)&bnb[c0];
    float4 m = *(const float4*)&bnm[c0];
    float4 vv = *(const float4*)&bnv[c0];
    float A0 = g.x * rsqrtf(vv.x + BN_EPS);
    float A1 = g.y * rsqrtf(vv.y + BN_EPS);
    float A2 = g.z * rsqrtf(vv.z + BN_EPS);
    float A3 = g.w * rsqrtf(vv.w + BN_EPS);
    float B0 = (bv.x - m.x) * A0 + bb.x;
    float B1 = (bv.y - m.y) * A1 + bb.y;
    float B2 = (bv.z - m.z) * A2 + bb.z;
    float B3 = (bv.w - m.w) * A3 + bb.w;
#pragma unroll
    for (int i = 0; i < 4; ++i) {
        int row = row0 + r0 + i;
        if (row >= N_NODES) break;
        unsigned int u0 = __half_as_ushort(__float2half(fmaxf(0.f, fmaf(acc[i][0], A0, B0))));
        unsigned int u1 = __half_as_ushort(__float2half(fmaxf(0.f, fmaf(acc[i][1], A1, B1))));
        unsigned int u2 = __half_as_ushort(__float2half(fmaxf(0.f, fmaf(acc[i][2], A2, B2))));
        unsigned int u3 = __half_as_ushort(__float2half(fmaxf(0.f, fmaf(acc[i][3], A3, B3))));
        *(uint2*)(out + (size_t)row * DIM + c0) = make_uint2(u0 | (u1 << 16), u2 | (u3 << 16));
    }
}

// ===========================================================================
// Tail: out = tanh(x @ W3p + b3p) @ pW2 + pb2; fp16 in, fp32 out.
// ===========================================================================
__global__ __launch_bounds__(256) void k_tail(const __half* __restrict__ xin,
                                              const float* __restrict__ W3p,
                                              const float* __restrict__ b3p,
                                              const float* __restrict__ pW2,
                                              const float* __restrict__ pb2,
                                              float* __restrict__ out) {
    __shared__ float sW1[4096];
    __shared__ float sW2[4096];
    __shared__ float sX[64 * LDX];
    int tid = threadIdx.x;
    int row0 = blockIdx.x * 64;

    for (int i = tid; i < 1024; i += 256) {
        ((float4*)sW1)[i] = ((const float4*)W3p)[i];
        ((float4*)sW2)[i] = ((const float4*)pW2)[i];
    }
    STAGE_H2F(xin, sX)
    __syncthreads();

    int cq = tid & 15, rq = tid >> 4;
    int c0 = cq * 4, r0 = rq * 4;
    float acc[4][4];

    // ---- GEMM 1: sX @ W3p ----
#pragma unroll
    for (int i = 0; i < 4; ++i)
#pragma unroll
        for (int j = 0; j < 4; ++j) acc[i][j] = 0.f;
#pragma unroll 4
    for (int k4 = 0; k4 < 16; ++k4) GEMM_STEP(sX, sW1)
    __syncthreads();

    {
        float4 bv = *(const float4*)&b3p[c0];
#pragma unroll
        for (int i = 0; i < 4; ++i) {
            float4 h;
            h.x = tanhf(acc[i][0] + bv.x);
            h.y = tanhf(acc[i][1] + bv.y);
            h.z = tanhf(acc[i][2] + bv.z);
            h.w = tanhf(acc[i][3] + bv.w);
            *(float4*)&sX[(r0 + i) * LDX + c0] = h;
        }
    }
    __syncthreads();

    // ---- GEMM 2: sX @ pW2 ----
#pragma unroll
    for (int i = 0; i < 4; ++i)
#pragma unroll
        for (int j = 0; j < 4; ++j) acc[i][j] = 0.f;
#pragma unroll 4
    for (int k4 = 0; k4 < 16; ++k4) GEMM_STEP(sX, sW2)

    float4 bv = *(const float4*)&pb2[c0];
#pragma unroll
    for (int i = 0; i < 4; ++i) {
        int row = row0 + r0 + i;
        if (row >= N_NODES) break;
        float4 o;
        o.x = acc[i][0] + bv.x;
        o.y = acc[i][1] + bv.y;
        o.z = acc[i][2] + bv.z;
        o.w = acc[i][3] + bv.w;
        *(float4*)(out + (size_t)row * DIM + c0) = o;
    }
}

// ===========================================================================
extern "C" void kernel_launch(void* const* d_in, const int* in_sizes, int n_in,
                              void* d_out, int out_size, void* d_ws, size_t ws_size,
                              hipStream_t stream) {
    const float* x     = (const float*)d_in[0];
    const int*   ei    = (const int*)d_in[1];
    const float* W1    = (const float*)d_in[2];
    const float* b1    = (const float*)d_in[3];
    const float* W2    = (const float*)d_in[4];
    const float* b2    = (const float*)d_in[5];
    const float* W3    = (const float*)d_in[6];
    const float* b3    = (const float*)d_in[7];
    const float* bn1_g = (const float*)d_in[8];
    const float* bn1_b = (const float*)d_in[9];
    const float* bn1_m = (const float*)d_in[10];
    const float* bn1_v = (const float*)d_in[11];
    const float* bn2_g = (const float*)d_in[12];
    const float* bn2_b = (const float*)d_in[13];
    const float* bn2_m = (const float*)d_in[14];
    const float* bn2_v = (const float*)d_in[15];
    const float* pW1   = (const float*)d_in[16];
    const float* pb1   = (const float*)d_in[17];
    const float* pW2   = (const float*)d_in[18];
    const float* pb2   = (const float*)d_in[19];
    float* out = (float*)d_out;

    // Layout note: deg..edges are contiguous so ONE memset zeroes deg, gcount,
    // row_off, cursor (harmlessly; overwritten by k_scan) and the edge pads.
    char* ws = (char*)d_ws;
    int*   deg      = (int*)ws;                      ws += 100352 * 4;
    int*   gcount   = (int*)ws;                      ws += 4 * 4;
    int*   row_off  = (int*)ws;                      ws += 100352 * 4;
    int*   cursor   = (int*)ws;                      ws += 100352 * 4;
    int2*  edges    = (int2*)ws;                     ws += (size_t)EDGE_CAP * 8;
    float* dinv     = (float*)ws;                    ws += 100352 * 4;
    float* W3p      = (float*)ws;                    ws += 4096 * 4;
    float* b3p      = (float*)ws;                    ws += 64 * 4;
    __half* xh      = (__half*)ws;                   ws += (size_t)N_NODES * DIM * 2;
    __half* hbuf    = (__half*)ws;                   ws += (size_t)N_NODES * DIM * 2;
    __half* abuf    = (__half*)ws;                   ws += (size_t)N_NODES * DIM * 2;

    const int blk = 256;
    int gE    = (N_EDGES + blk - 1) / blk;       // 3125
    int gCvt  = 6250;                            // covers 1.6M cvt + 800k count
    int gAgg  = N_NODES / 4;                     // 25000 (exact)
    int gTile = (N_NODES + 63) / 64;             // 1563

    size_t zbytes = (size_t)(100352 * 3 + 4) * 4 + (size_t)EDGE_CAP * 8;
    hipMemsetAsync(deg, 0, zbytes, stream);
    k_cvt_count<<<gCvt, blk, 0, stream>>>(x, xh, ei + N_EDGES, deg);
    k_scan_fuse<<<99, blk, 0, stream>>>(deg, row_off, cursor, dinv, gcount,
                                        W3, b3, pW1, pb1, W3p, b3p);
    k_build<<<gE, blk, 0, stream>>>(ei, dinv, cursor, edges);

    // ---- layer 1 ----
    k_aggregate<<<gAgg, blk, 0, stream>>>(xh, row_off, deg, edges, dinv, abuf);
    k_gemm_bn_h<<<gTile, blk, 0, stream>>>(abuf, W1, b1, bn1_g, bn1_b, bn1_m, bn1_v, hbuf);

    // ---- layer 2 ----
    k_aggregate<<<gAgg, blk, 0, stream>>>(hbuf, row_off, deg, edges, dinv, abuf);
    k_gemm_bn_h<<<gTile, blk, 0, stream>>>(abuf, W2, b2, bn2_g, bn2_b, bn2_m, bn2_v, hbuf);

    // ---- layer 3 + fused predictor ----
    k_aggregate<<<gAgg, blk, 0, stream>>>(hbuf, row_off, deg, edges, dinv, abuf);
    k_tail<<<gTile, blk, 0, stream>>>(abuf, W3p, b3p, pW2, pb2, out);
}